// Round 11
// baseline (146.847 us; speedup 1.0000x reference)
//
#include <hip/hip_runtime.h>

typedef __attribute__((ext_vector_type(4))) float f32x4;
typedef __attribute__((ext_vector_type(4))) int   i32x4;
typedef __attribute__((ext_vector_type(8))) int   i32x8;
typedef unsigned short u16;
typedef unsigned int u32;
typedef unsigned char u8;

#define DEV static __device__ __forceinline__

// problem sizes (fixed by the reference)
#define CB 4
#define CN 2048
#define CD 1024
#define CM 8192   // CB*CN

DEV u16 f2bf(float f) {
  u32 u = __float_as_uint(f);
  u = (u + 0x7FFFu + ((u >> 16) & 1u)) >> 16;
  return (u16)u;
}
DEV float bf2f(u16 h) { return __uint_as_float(((u32)h) << 16); }

DEV u8 f2fp8(float f) {
  return (u8)(__builtin_amdgcn_cvt_pk_fp8_f32(f, 0.f, 0, false) & 0xff);
}
DEV u32 pk_fp8x4(float a, float b, float c, float d) {
  const int p01 = __builtin_amdgcn_cvt_pk_fp8_f32(a, b, 0, false);
  const int p23 = __builtin_amdgcn_cvt_pk_fp8_f32(c, d, 0, false);
  return (u32)(p01 & 0xffff) | ((u32)(p23 & 0xffff) << 16);
}

#define GLD16(gsrc, ldst)                                                        \
  __builtin_amdgcn_global_load_lds(                                              \
      (const __attribute__((address_space(1))) void*)(gsrc),                     \
      (__attribute__((address_space(3))) void*)(ldst), 16, 0, 0)

#define SBAR()  asm volatile("s_barrier" ::: "memory")
#define WAITL() asm volatile("s_waitcnt lgkmcnt(0)" ::: "memory")
#define WAITV0() asm volatile("s_waitcnt vmcnt(0)" ::: "memory")

// unit-scale (E8M0=127) fp8xfp8 K=128 MFMA
#define MFMA_F8(a, b, c)                                                         \
  __builtin_amdgcn_mfma_scale_f32_16x16x128_f8f6f4((a), (b), (c), 0, 0, 0, 127,  \
                                                   0, 127)

// ---------------------------------------------------------------------------
// fp8 LDS tiles: [rows][128 bytes], XOR swizzle byte ^= ((byte>>7)&7)<<4
// (proven 0-conflict 128B-row layout). Per-lane fragment = 32B (2x b128).
// ---------------------------------------------------------------------------
DEV i32x8 lds_read_f8(const char* region, int row, int kbyte) {
  int b0 = row * 128 + kbyte;      b0 ^= ((b0 >> 7) & 7) << 4;
  int b1 = row * 128 + kbyte + 16; b1 ^= ((b1 >> 7) & 7) << 4;
  i32x4 lo = *(const i32x4*)(region + b0);
  i32x4 hi = *(const i32x4*)(region + b1);
  i32x8 r;
  r[0] = lo[0]; r[1] = lo[1]; r[2] = lo[2]; r[3] = lo[3];
  r[4] = hi[0]; r[5] = hi[1]; r[6] = hi[2]; r[7] = hi[3];
  return r;
}

// stage fp8 [128 rows][128B] (16KB) with a 256-thread block: 1024 chunks,
// 4/thread, pre-swizzled global source, linear LDS dest (wave-contiguous).
DEV void stage_f8_128t(const u8* __restrict__ g, int ld, int row0, int kb,
                       char* dst, int tid) {
#pragma unroll
  for (int s = 0; s < 4; ++s) {
    const int c = tid + s * 256;        // 0..1023
    const int row = c >> 3, sl = c & 7;
    const int lo = sl ^ (row & 7);
    GLD16(g + (size_t)(row0 + row) * ld + kb + lo * 16, dst + c * 16);
  }
}

// ---------------------------------------------------------------------------
// fp8 128x128 core (m97 structure): 256 threads = 4 waves (2x2), wave tile
// 64x64, acc[4][4], K-tile 128. LDS 64KB = 2 buf x (A 16KB @0 + B 16KB
// @16384) -> 2 blocks/CU: the end-of-tile drain of one block overlaps the
// other block's MFMA (m114 mechanism) instead of idling the CU.
// ---------------------------------------------------------------------------
DEV void gemm_f8_128(const u8* __restrict__ A, int lda,
                     const u8* __restrict__ Bt, int ldb,
                     int m0, int n0, int K, char* lds, f32x4 (&acc)[4][4])
{
  const int tid = threadIdx.x;
  const int lane = tid & 63;
  const int wid = tid >> 6;            // 0..3
  const int wr = wid >> 1, wc = wid & 1;
  const int lr = lane & 15, kg = lane >> 4;
  const int nt = K >> 7;

  char* buf0 = lds;
  char* buf1 = lds + 32768;

  stage_f8_128t(A,  lda, m0, 0, buf0,         tid);
  stage_f8_128t(Bt, ldb, n0, 0, buf0 + 16384, tid);
  WAITV0();
  SBAR();

  for (int t = 0; t < nt; ++t) {
    char* cur = (t & 1) ? buf1 : buf0;
    char* nxt = (t & 1) ? buf0 : buf1;
    const int kb1 = (t + 1) << 7;

    if (t + 1 < nt) {
      stage_f8_128t(A,  lda, m0, kb1, nxt,         tid);
      stage_f8_128t(Bt, ldb, n0, kb1, nxt + 16384, tid);
    }

    i32x8 Af[4], Bf[4];
#pragma unroll
    for (int m = 0; m < 4; ++m)
      Af[m] = lds_read_f8(cur, wr * 64 + m * 16 + lr, kg * 32);
#pragma unroll
    for (int n = 0; n < 4; ++n)
      Bf[n] = lds_read_f8(cur + 16384, wc * 64 + n * 16 + lr, kg * 32);

    __builtin_amdgcn_s_setprio(1);
#pragma unroll
    for (int m = 0; m < 4; ++m)
#pragma unroll
      for (int n = 0; n < 4; ++n)
        acc[m][n] = MFMA_F8(Af[m], Bf[n], acc[m][n]);
    __builtin_amdgcn_s_setprio(0);

    WAITV0();
    SBAR();
  }
}

// ---------------------------------------------------------------------------
// f32 -> fp8 convert; z=1 (x2) also accumulates exact f32 colsum partials.
// z=0 blocks 0..31 additionally zero lsum (replaces hipMemsetAsync).
// ---------------------------------------------------------------------------
__global__ __launch_bounds__(256) void cvt_kernel(
    const float* __restrict__ x1, u8* __restrict__ x1f8,
    const float* __restrict__ x2, u8* __restrict__ x2f8,
    float* __restrict__ csum, float* __restrict__ lsum)
{
  const int z = blockIdx.y;
  const float* in = z ? x2 : x1;
  u8* out = z ? x2f8 : x1f8;
  const int bx = blockIdx.x, tid = threadIdx.x;
  if (!z && bx < 32) lsum[bx * 256 + tid] = 0.f;   // zero ls (8192 f32)
  const int col = tid * 4;
  float4 s4 = {0.f, 0.f, 0.f, 0.f};
#pragma unroll 4
  for (int r = 0; r < 32; ++r) {
    const size_t row = (size_t)bx * 32 + r;
    const float4 v = *(const float4*)(in + row * CD + col);
    *(u32*)(out + row * CD + col) = pk_fp8x4(v.x, v.y, v.z, v.w);
    if (z) { s4.x += v.x; s4.y += v.y; s4.z += v.z; s4.w += v.w; }
  }
  if (z) {
    const int b = bx >> 6;   // 32 rows/block, 2048 rows/batch
    float* cb = csum + b * CD + col;
    atomicAdd(cb + 0, s4.x);
    atomicAdd(cb + 1, s4.y);
    atomicAdd(cb + 2, s4.z);
    atomicAdd(cb + 3, s4.w);
  }
}

// W [1024][1024] f32 -> WT [n][k] fp8; z selects Wq/Wk/Wv.
// z=0, by=0 blocks also zero csum (runs BEFORE cvt in launch order).
__global__ __launch_bounds__(256) void transpose_w_kernel(
    const float* __restrict__ Wq, const float* __restrict__ Wk,
    const float* __restrict__ Wv, u8* __restrict__ WqT8,
    u8* __restrict__ WkT8, u8* __restrict__ WvT8, float* __restrict__ csum)
{
  __shared__ float tile[32][33];
  const int z = blockIdx.z;
  const float* W = (z == 0) ? Wq : ((z == 1) ? Wk : Wv);
  u8* WT = (z == 0) ? WqT8 : ((z == 1) ? WkT8 : WvT8);
  const int tx = threadIdx.x, ty = threadIdx.y;   // 32 x 8
  const int bx = blockIdx.x, by = blockIdx.y;
  const int ft = ty * 32 + tx;
  if (z == 0 && by == 0 && ft < 128) csum[bx * 128 + ft] = 0.f;  // 4096 f32
#pragma unroll
  for (int i = 0; i < 4; ++i)
    tile[ty + i * 8][tx] = W[(size_t)(by * 32 + ty + i * 8) * CD + bx * 32 + tx];
  __syncthreads();
#pragma unroll
  for (int i = 0; i < 4; ++i)
    WT[(size_t)(bx * 32 + ty + i * 8) * CD + by * 32 + tx] =
        f2fp8(tile[tx][ty + i * 8]);
}

// ---------------------------------------------------------------------------
// EXACT vsum: vsum[b][d] = sum_k csum[b][k]*Wv[k][d] + 2048*bv[d]  (all f32)
// ---------------------------------------------------------------------------
__global__ __launch_bounds__(256) void vsum_mv_kernel(
    const float* __restrict__ csum, const float* __restrict__ Wv,
    const float* __restrict__ bv, float* __restrict__ vsum)
{
  __shared__ float sh[256];
  const int dc = blockIdx.x, b = blockIdx.y;
  const int tid = threadIdx.x;
  const int dl = tid & 127, kh = tid >> 7;
  const int d = dc * 128 + dl;
  const float* cb = csum + b * CD;
  float p0 = 0.f, p1 = 0.f, p2 = 0.f, p3 = 0.f;
  const int k0 = kh * 512;
  for (int k = k0; k < k0 + 512; k += 4) {
    p0 += cb[k + 0] * Wv[(size_t)(k + 0) * CD + d];
    p1 += cb[k + 1] * Wv[(size_t)(k + 1) * CD + d];
    p2 += cb[k + 2] * Wv[(size_t)(k + 2) * CD + d];
    p3 += cb[k + 3] * Wv[(size_t)(k + 3) * CD + d];
  }
  sh[tid] = (p0 + p1) + (p2 + p3);
  __syncthreads();
  if (tid < 128)
    vsum[b * CD + dc * 128 + tid] =
        sh[tid] + sh[tid + 128] + 2048.0f * bv[dc * 128 + tid];
}

// ---------------------------------------------------------------------------
// fused Q|K projections (128^2 fp8 core): grid (64,16)=1024, 2 clean rounds.
// by 0..7 -> Q n-tiles, 8..15 -> K n-tiles.
// ---------------------------------------------------------------------------
__global__ __launch_bounds__(256, 2) void qk_kernel(
    const u8* __restrict__ x1f8, const u8* __restrict__ x2f8,
    const u8* __restrict__ WqT8, const u8* __restrict__ WkT8,
    const float* __restrict__ bq, const float* __restrict__ bk,
    u8* __restrict__ Qf8, u8* __restrict__ Kf8)
{
  extern __shared__ char smem_raw[];
  const int flat = blockIdx.y * 64 + blockIdx.x;      // nwg=1024
  const int s = (flat & 7) * 128 + (flat >> 3);       // XCD swizzle
  const int bx = s & 63, by = s >> 6;
  const int sel = by >> 3;
  const int m0 = bx * 128, n0 = (by & 7) * 128;
  const u8* A  = sel ? x2f8 : x1f8;
  const u8* Bt = sel ? WkT8 : WqT8;
  const float* bias = sel ? bk : bq;
  u8* Y = sel ? Kf8 : Qf8;

  f32x4 acc[4][4] = {};
  gemm_f8_128(A, CD, Bt, CD, m0, n0, CD, smem_raw, acc);

  const int tid = threadIdx.x, lane = tid & 63, wid = tid >> 6;
  const int wr = wid >> 1, wc = wid & 1, lr = lane & 15, kg = lane >> 4;
#pragma unroll
  for (int mi = 0; mi < 4; ++mi)
#pragma unroll
    for (int ni = 0; ni < 4; ++ni) {
      const int col = n0 + wc * 64 + ni * 16 + lr;
      const float bcol = bias[col];
#pragma unroll
      for (int j = 0; j < 4; ++j) {
        const int row = m0 + wr * 64 + mi * 16 + kg * 4 + j;
        Y[(size_t)row * CD + col] = f2fp8(acc[mi][ni][j] + bcol);
      }
    }
}

// ---------------------------------------------------------------------------
// V projection (128^2 fp8 core) -> Vt8[b][d][n] via LDS transpose.
// grid (64,8)=512, 1 clean round.
// ---------------------------------------------------------------------------
__global__ __launch_bounds__(256, 2) void v_kernel(
    const u8* __restrict__ x2f8, const u8* __restrict__ WvT8,
    const float* __restrict__ bv, u8* __restrict__ Vt8)
{
  extern __shared__ char smem_raw[];
  const int flat = blockIdx.y * 64 + blockIdx.x;      // nwg=512
  const int s = (flat & 7) * 64 + (flat >> 3);
  const int bx = s & 63, by = s >> 6;                 // 64 m-tiles, 8 d-tiles
  const int m0 = bx * 128, n0 = by * 128;

  f32x4 acc[4][4] = {};
  gemm_f8_128(x2f8, CD, WvT8, CD, m0, n0, CD, smem_raw, acc);

  const int tid = threadIdx.x, lane = tid & 63, wid = tid >> 6;
  const int wr = wid >> 1, wc = wid & 1, lr = lane & 15, kg = lane >> 4;
  const int b = m0 >> 11;              // batch
  const int nwb = m0 & (CN - 1);       // n-offset within batch
  u8* ldsT = (u8*)smem_raw;            // [128 d][136] u8 = 17.4KB

#pragma unroll
  for (int ni = 0; ni < 4; ++ni) {
    const int cl = wc * 64 + ni * 16 + lr;           // d within tile, 0..127
    const float bcol = bv[n0 + cl];
#pragma unroll
    for (int mi = 0; mi < 4; ++mi) {
      const int rowb = wr * 64 + mi * 16 + kg * 4;   // n within tile, 4-aligned
      *(u32*)(ldsT + cl * 136 + rowb) =
          pk_fp8x4(acc[mi][ni][0] + bcol, acc[mi][ni][1] + bcol,
                   acc[mi][ni][2] + bcol, acc[mi][ni][3] + bcol);
    }
  }
  WAITL();
  SBAR();
  // coalesced copy-out: 128 d x 128 n fp8 = 1024 16B chunks, 4/thread
#pragma unroll
  for (int i = 0; i < 4; ++i) {
    const int c = tid + i * 256;
    const int dl = c >> 3;             // 0..127
    const int nk = c & 7;              // 16B chunk
    i32x4 vv = *(const i32x4*)(ldsT + dl * 136 + nk * 16);
    *(i32x4*)(Vt8 + ((size_t)b * CD + n0 + dl) * CN + nwb + nk * 16) = vv;
  }
}

// ---------------------------------------------------------------------------
// P/4 = exp(Q*K^T/32)/4 (fp8), row sums l (f32) via atomics.
// grid (16,16,4)=1024, 2 clean rounds.
// ---------------------------------------------------------------------------
__global__ __launch_bounds__(256, 2) void scores_kernel(
    const u8* __restrict__ Q, const u8* __restrict__ Km,
    u8* __restrict__ P, float* __restrict__ lsum)
{
  extern __shared__ char smem_raw[];
  const int flat = (blockIdx.z * 16 + blockIdx.y) * 16 + blockIdx.x;  // 1024
  const int s = (flat & 7) * 128 + (flat >> 3);
  const int bx = s & 15, by = (s >> 4) & 15, bz = s >> 8;
  const int m0 = bx * 128, n0 = by * 128;
  const u8* A  = Q  + (size_t)bz * CN * CD;
  const u8* Bt = Km + (size_t)bz * CN * CD;

  f32x4 acc[4][4] = {};
  gemm_f8_128(A, CD, Bt, CD, m0, n0, CD, smem_raw, acc);

  const int tid = threadIdx.x, lane = tid & 63, wid = tid >> 6;
  const int wr = wid >> 1, wc = wid & 1, lr = lane & 15, kg = lane >> 4;
  u8* Pb = P + (size_t)bz * CN * CN;
  float* lb = lsum + (size_t)bz * CN;
  const float sc = 0.03125f * 1.4426950408889634f;
#pragma unroll
  for (int mi = 0; mi < 4; ++mi) {
    float rs[4] = {0.f, 0.f, 0.f, 0.f};
#pragma unroll
    for (int ni = 0; ni < 4; ++ni) {
      const int col = n0 + wc * 64 + ni * 16 + lr;
#pragma unroll
      for (int j = 0; j < 4; ++j) {
        const int row = m0 + wr * 64 + mi * 16 + kg * 4 + j;
        const float pv = exp2f(acc[mi][ni][j] * sc);
        rs[j] += pv;
        Pb[(size_t)row * CN + col] = f2fp8(pv * 0.25f);
      }
    }
#pragma unroll
    for (int j = 0; j < 4; ++j) {
      float v = rs[j];
      v += __shfl_xor(v, 1);
      v += __shfl_xor(v, 2);
      v += __shfl_xor(v, 4);
      v += __shfl_xor(v, 8);
      if (lr == 0)
        atomicAdd(&lb[m0 + wr * 64 + mi * 16 + kg * 4 + j], v);
    }
  }
}

// ---------------------------------------------------------------------------
// ctx = (vsum - 4*(P/4 @ V)/l) / (N-1)  -> bf16. grid (16,8,4)=512, 1 round.
// ---------------------------------------------------------------------------
__global__ __launch_bounds__(256, 2) void pv_kernel(
    const u8* __restrict__ P, const u8* __restrict__ Vt,
    const float* __restrict__ lsum, const float* __restrict__ vsum,
    u16* __restrict__ ctx)
{
  extern __shared__ char smem_raw[];
  const int flat = (blockIdx.z * 8 + blockIdx.y) * 16 + blockIdx.x;  // 512
  const int s = (flat & 7) * 64 + (flat >> 3);
  const int bx = s & 15, by = (s >> 4) & 7, bz = s >> 7;
  const int m0 = bx * 128, n0 = by * 128;
  const u8* A  = P  + (size_t)bz * CN * CN;   // [2048][2048] fp8
  const u8* Bt = Vt + (size_t)bz * CD * CN;   // [1024][2048] fp8

  f32x4 acc[4][4] = {};
  gemm_f8_128(A, CN, Bt, CN, m0, n0, CN, smem_raw, acc);

  const int tid = threadIdx.x, lane = tid & 63, wid = tid >> 6;
  const int wr = wid >> 1, wc = wid & 1, lr = lane & 15, kg = lane >> 4;
  const float inv_nm1 = 1.0f / (float)(CN - 1);
#pragma unroll
  for (int mi = 0; mi < 4; ++mi)
#pragma unroll
    for (int j = 0; j < 4; ++j) {
      const int row = m0 + wr * 64 + mi * 16 + kg * 4 + j;
      const float rl = 4.0f / lsum[(size_t)bz * CN + row];
#pragma unroll
      for (int ni = 0; ni < 4; ++ni) {
        const int col = n0 + wc * 64 + ni * 16 + lr;
        const float cv = (vsum[bz * CD + col] - acc[mi][ni][j] * rl) * inv_nm1;
        ctx[(size_t)(bz * CN + row) * CD + col] = f2bf(cv);
      }
    }
}

// LayerNorm + ReLU per row of 1024: bf16 ctx in, f32 out
__global__ __launch_bounds__(256) void ln_relu_kernel(
    const u16* __restrict__ ctx, const float* __restrict__ gamma,
    const float* __restrict__ beta, float* __restrict__ out)
{
  const u16* x = ctx + (size_t)blockIdx.x * CD;
  const int t = threadIdx.x;
  const ushort4 uv = ((const ushort4*)x)[t];
  float v0 = bf2f(uv.x), v1 = bf2f(uv.y), v2 = bf2f(uv.z), v3 = bf2f(uv.w);
  float s = v0 + v1 + v2 + v3;
  float q = v0 * v0 + v1 * v1 + v2 * v2 + v3 * v3;
#pragma unroll
  for (int off = 1; off < 64; off <<= 1) {
    s += __shfl_xor(s, off);
    q += __shfl_xor(q, off);
  }
  __shared__ float ss[4], qq[4];
  const int w = t >> 6, lane = t & 63;
  if (lane == 0) { ss[w] = s; qq[w] = q; }
  __syncthreads();
  s = ss[0] + ss[1] + ss[2] + ss[3];
  q = qq[0] + qq[1] + qq[2] + qq[3];
  const float mean = s * (1.0f / CD);
  const float var  = q * (1.0f / CD) - mean * mean;
  const float rstd = rsqrtf(var + 1e-5f);
  const float4 g  = ((const float4*)gamma)[t];
  const float4 bb = ((const float4*)beta)[t];
  float4 o;
  o.x = fmaxf(0.f, (v0 - mean) * rstd * g.x + bb.x);
  o.y = fmaxf(0.f, (v1 - mean) * rstd * g.y + bb.y);
  o.z = fmaxf(0.f, (v2 - mean) * rstd * g.z + bb.z);
  o.w = fmaxf(0.f, (v3 - mean) * rstd * g.w + bb.w);
  ((float4*)(out + (size_t)blockIdx.x * CD))[t] = o;
}

// ---------------------------------------------------------------------------
extern "C" void kernel_launch(void* const* d_in, const int* in_sizes, int n_in,
                              void* d_out, int out_size, void* d_ws, size_t ws_size,
                              hipStream_t stream)
{
  (void)in_sizes; (void)n_in; (void)out_size; (void)ws_size;
  const float* x1    = (const float*)d_in[0];
  const float* x2    = (const float*)d_in[1];
  const float* Wq    = (const float*)d_in[2];
  const float* bq    = (const float*)d_in[3];
  const float* Wk    = (const float*)d_in[4];
  const float* bk    = (const float*)d_in[5];
  const float* Wv    = (const float*)d_in[6];
  const float* bv    = (const float*)d_in[7];
  const float* gamma = (const float*)d_in[8];
  const float* beta  = (const float*)d_in[9];
  float* out = (float*)d_out;

  const int LDS_CORE = 65536;
  hipFuncSetAttribute((const void*)qk_kernel,
                      hipFuncAttributeMaxDynamicSharedMemorySize, LDS_CORE);
  hipFuncSetAttribute((const void*)scores_kernel,
                      hipFuncAttributeMaxDynamicSharedMemorySize, LDS_CORE);
  hipFuncSetAttribute((const void*)v_kernel,
                      hipFuncAttributeMaxDynamicSharedMemorySize, LDS_CORE);
  hipFuncSetAttribute((const void*)pv_kernel,
                      hipFuncAttributeMaxDynamicSharedMemorySize, LDS_CORE);

  char* p = (char*)d_ws;
  auto alloc = [&](size_t bytes) -> char* {
    char* r = p;
    p += (bytes + 255) & ~(size_t)255;
    return r;
  };
  u8*  x1f8  = (u8*)alloc((size_t)CM * CD);
  u8*  x2f8  = (u8*)alloc((size_t)CM * CD);
  u8*  WqT8  = (u8*)alloc((size_t)CD * CD);
  u8*  WkT8  = (u8*)alloc((size_t)CD * CD);
  u8*  WvT8  = (u8*)alloc((size_t)CD * CD);
  u8*  Qf8   = (u8*)alloc((size_t)CM * CD);
  u8*  Kf8   = (u8*)alloc((size_t)CM * CD);
  u8*  Vt8   = (u8*)alloc((size_t)CM * CD);
  u8*  Pf8   = (u8*)alloc((size_t)CB * CN * CN);
  u16* ctxb  = (u16*)alloc((size_t)CM * CD * 2);
  float* ls  = (float*)alloc((size_t)CB * CN * 4);
  float* vs  = (float*)alloc((size_t)CB * CD * 4);
  float* cs  = (float*)alloc((size_t)CB * CD * 4);

  // W transposes -> fp8 + zero csum (must precede cvt)
  {
    dim3 g(32, 32, 3), blk(32, 8);
    transpose_w_kernel<<<g, blk, 0, stream>>>(Wq, Wk, Wv, WqT8, WkT8, WvT8, cs);
  }

  // f32 -> fp8 inputs + exact colsum(x2) partials + zero lsum
  {
    dim3 g(256, 2);
    cvt_kernel<<<g, 256, 0, stream>>>(x1, x1f8, x2, x2f8, cs, ls);
  }

  // exact vsum = colsum(x2).Wv + 2048*bv  (f32)
  {
    dim3 g(8, CB);
    vsum_mv_kernel<<<g, 256, 0, stream>>>(cs, Wv, bv, vs);
  }

  // fused Q|K projections (fp8 128^2 core, 1024 blocks)
  {
    dim3 g(64, 16);
    qk_kernel<<<g, 256, LDS_CORE, stream>>>(x1f8, x2f8, WqT8, WkT8, bq, bk,
                                            Qf8, Kf8);
  }

  // V projection -> Vt8 (512 blocks)
  {
    dim3 g(64, 8);
    v_kernel<<<g, 256, LDS_CORE, stream>>>(x2f8, WvT8, bv, Vt8);
  }

  // P/4 = exp(QK^T/32)/4 (fp8), l = rowsum (1024 blocks)
  {
    dim3 g(16, 16, CB);
    scores_kernel<<<g, 256, LDS_CORE, stream>>>(Qf8, Kf8, Pf8, ls);
  }

  // ctx = (vsum - 4*P@V/l)/(N-1) -> bf16 (512 blocks)
  {
    dim3 g(16, 8, CB);
    pv_kernel<<<g, 256, LDS_CORE, stream>>>(Pf8, Vt8, ls, vs, ctxb);
  }

  // LayerNorm + ReLU (bf16 in, f32 out)
  ln_relu_kernel<<<CM, 256, 0, stream>>>(ctxb, gamma, beta, out);
}

// Round 12
// 146.389 us; speedup vs baseline: 1.0031x; 1.0031x over previous
//
#include <hip/hip_runtime.h>

typedef __attribute__((ext_vector_type(4))) float f32x4;
typedef __attribute__((ext_vector_type(4))) int   i32x4;
typedef __attribute__((ext_vector_type(8))) int   i32x8;
typedef unsigned short u16;
typedef unsigned int u32;
typedef unsigned char u8;

#define DEV static __device__ __forceinline__

// problem sizes (fixed by the reference)
#define CB 4
#define CN 2048
#define CD 1024
#define CM 8192   // CB*CN

DEV u16 f2bf(float f) {
  u32 u = __float_as_uint(f);
  u = (u + 0x7FFFu + ((u >> 16) & 1u)) >> 16;
  return (u16)u;
}
DEV float bf2f(u16 h) { return __uint_as_float(((u32)h) << 16); }

DEV u8 f2fp8(float f) {
  return (u8)(__builtin_amdgcn_cvt_pk_fp8_f32(f, 0.f, 0, false) & 0xff);
}
DEV u32 pk_fp8x4(float a, float b, float c, float d) {
  const int p01 = __builtin_amdgcn_cvt_pk_fp8_f32(a, b, 0, false);
  const int p23 = __builtin_amdgcn_cvt_pk_fp8_f32(c, d, 0, false);
  return (u32)(p01 & 0xffff) | ((u32)(p23 & 0xffff) << 16);
}

#define GLD16(gsrc, ldst)                                                        \
  __builtin_amdgcn_global_load_lds(                                              \
      (const __attribute__((address_space(1))) void*)(gsrc),                     \
      (__attribute__((address_space(3))) void*)(ldst), 16, 0, 0)

#define SBAR()  asm volatile("s_barrier" ::: "memory")
#define WAITL() asm volatile("s_waitcnt lgkmcnt(0)" ::: "memory")
#define WAITV(n) asm volatile("s_waitcnt vmcnt(" #n ")" ::: "memory")

// unit-scale (E8M0=127) fp8xfp8 K=128 MFMA
#define MFMA_F8(a, b, c)                                                         \
  __builtin_amdgcn_mfma_scale_f32_16x16x128_f8f6f4((a), (b), (c), 0, 0, 0, 127,  \
                                                   0, 127)

// ---------------------------------------------------------------------------
// fp8 LDS tiles: [rows][128 bytes], XOR swizzle byte ^= ((byte>>7)&7)<<4
// (proven 0-conflict 128B-row layout). Per-lane fragment = 32B (2x b128).
// ---------------------------------------------------------------------------
DEV i32x8 lds_read_f8(const char* region, int row, int kbyte) {
  int b0 = row * 128 + kbyte;      b0 ^= ((b0 >> 7) & 7) << 4;
  int b1 = row * 128 + kbyte + 16; b1 ^= ((b1 >> 7) & 7) << 4;
  i32x4 lo = *(const i32x4*)(region + b0);
  i32x4 hi = *(const i32x4*)(region + b1);
  i32x8 r;
  r[0] = lo[0]; r[1] = lo[1]; r[2] = lo[2]; r[3] = lo[3];
  r[4] = hi[0]; r[5] = hi[1]; r[6] = hi[2]; r[7] = hi[3];
  return r;
}

// stage fp8 [128 rows][128B] (16KB) with a 256-thread block: 1024 chunks,
// 4/thread, pre-swizzled global source, linear LDS dest.
DEV void stage_f8_128t(const u8* __restrict__ g, int ld, int row0, int kb,
                       char* dst, int tid) {
#pragma unroll
  for (int s = 0; s < 4; ++s) {
    const int c = tid + s * 256;        // 0..1023
    const int row = c >> 3, sl = c & 7;
    const int lo = sl ^ (row & 7);
    GLD16(g + (size_t)(row0 + row) * ld + kb + lo * 16, dst + c * 16);
  }
}

// ---------------------------------------------------------------------------
// fp8 128x128 core, 4-segment counted-wait pipeline. 256 threads = 4 waves
// (2x2), wave tile 64x64, acc[4][4], K-tile 128. LDS 64KB (2 buf) -> 2
// blocks/CU.
//
// Stage split: sA_i = A rows {i*16..+15} u {64+i*16..+15} (1 load/thread) —
// exactly the rows seg_i reads (wr=0 first range, wr=1 second).
// Issue: seg0 -> B(t+1) (4 loads) + sA_0(t+1); seg_i -> sA_i(t+1).
// Queue ledger (oldest->newest) at end of each seg is exactly 8 entries;
// waits: seg0/1/2 vmcnt(7) [drains sA_{i+1}(t), issued 3 segs (~700+cyc)
// earlier], seg3 vmcnt(3) [drains B+sA_0(t+1), keeps sA_1..3(t+1) in flight
// across the boundary — race-free: seg0(t+1) reads only B+sA_0 regions,
// disjoint from the in-flight sA_1..3 writes]. Last tile: {2,1,0,-}.
// No vmcnt(0) in the steady loop.
// ---------------------------------------------------------------------------
DEV void gemm_f8_128(const u8* __restrict__ A, int lda,
                     const u8* __restrict__ Bt, int ldb,
                     int m0, int n0, int K, char* lds, f32x4 (&acc)[4][4])
{
  const int tid = threadIdx.x;
  const int lane = tid & 63;
  const int wid = tid >> 6;            // 0..3
  const int wr = wid >> 1, wc = wid & 1;
  const int lr = lane & 15, kg = lane >> 4;
  const int nt = K >> 7;

  char* buf0 = lds;
  char* buf1 = lds + 32768;

  // per-thread sA chunk coords (1 chunk each seg)
  const int sub = tid >> 3;                        // 0..31
  const int sl  = tid & 7;
  const int base_r = (sub >> 4) * 64 + (sub & 15); // 0..15 or 64..79

  stage_f8_128t(A,  lda, m0, 0, buf0,         tid);
  stage_f8_128t(Bt, ldb, n0, 0, buf0 + 16384, tid);
  WAITV(0);
  SBAR();

  for (int t = 0; t < nt; ++t) {
    char* cur = (t & 1) ? buf1 : buf0;
    char* nxt = (t & 1) ? buf0 : buf1;
    const int kb1 = (t + 1) << 7;
    const bool pf = (t + 1 < nt);

    i32x8 Bf[4];
#pragma unroll
    for (int i = 0; i < 4; ++i) {
      // ---- seg i: reads
      if (i == 0) {
#pragma unroll
        for (int n = 0; n < 4; ++n)
          Bf[n] = lds_read_f8(cur + 16384, wc * 64 + n * 16 + lr, kg * 32);
      }
      i32x8 Af = lds_read_f8(cur, wr * 64 + i * 16 + lr, kg * 32);

      // stage issues
      if (pf) {
        if (i == 0) stage_f8_128t(Bt, ldb, n0, kb1, nxt + 16384, tid);
        const int lrow = base_r + i * 16;
        const int lo = sl ^ (lrow & 7);
        GLD16(A + (size_t)(m0 + lrow) * lda + kb1 + lo * 16,
              nxt + lrow * 128 + sl * 16);
      }

      WAITL();
      __builtin_amdgcn_sched_barrier(0);
      __builtin_amdgcn_s_setprio(1);
#pragma unroll
      for (int n = 0; n < 4; ++n)
        acc[i][n] = MFMA_F8(Af, Bf[n], acc[i][n]);
      __builtin_amdgcn_s_setprio(0);

      // counted end-of-seg wait
      if (pf) {
        if (i < 3) { WAITV(7); } else { WAITV(3); }
      } else {
        if (i == 0)      { WAITV(2); }
        else if (i == 1) { WAITV(1); }
        else if (i == 2) { WAITV(0); }
        // i==3: nothing outstanding
      }
      SBAR();
    }
  }
}

// ---------------------------------------------------------------------------
// f32 -> fp8 convert; z=1 (x2) also accumulates exact f32 colsum partials.
// z=0 blocks 0..31 additionally zero lsum (replaces hipMemsetAsync).
// ---------------------------------------------------------------------------
__global__ __launch_bounds__(256) void cvt_kernel(
    const float* __restrict__ x1, u8* __restrict__ x1f8,
    const float* __restrict__ x2, u8* __restrict__ x2f8,
    float* __restrict__ csum, float* __restrict__ lsum)
{
  const int z = blockIdx.y;
  const float* in = z ? x2 : x1;
  u8* out = z ? x2f8 : x1f8;
  const int bx = blockIdx.x, tid = threadIdx.x;
  if (!z && bx < 32) lsum[bx * 256 + tid] = 0.f;   // zero ls (8192 f32)
  const int col = tid * 4;
  float4 s4 = {0.f, 0.f, 0.f, 0.f};
#pragma unroll 4
  for (int r = 0; r < 32; ++r) {
    const size_t row = (size_t)bx * 32 + r;
    const float4 v = *(const float4*)(in + row * CD + col);
    *(u32*)(out + row * CD + col) = pk_fp8x4(v.x, v.y, v.z, v.w);
    if (z) { s4.x += v.x; s4.y += v.y; s4.z += v.z; s4.w += v.w; }
  }
  if (z) {
    const int b = bx >> 6;   // 32 rows/block, 2048 rows/batch
    float* cb = csum + b * CD + col;
    atomicAdd(cb + 0, s4.x);
    atomicAdd(cb + 1, s4.y);
    atomicAdd(cb + 2, s4.z);
    atomicAdd(cb + 3, s4.w);
  }
}

// W [1024][1024] f32 -> WT [n][k] fp8; z selects Wq/Wk/Wv.
// z=0, by=0 blocks also zero csum (runs BEFORE cvt in launch order).
__global__ __launch_bounds__(256) void transpose_w_kernel(
    const float* __restrict__ Wq, const float* __restrict__ Wk,
    const float* __restrict__ Wv, u8* __restrict__ WqT8,
    u8* __restrict__ WkT8, u8* __restrict__ WvT8, float* __restrict__ csum)
{
  __shared__ float tile[32][33];
  const int z = blockIdx.z;
  const float* W = (z == 0) ? Wq : ((z == 1) ? Wk : Wv);
  u8* WT = (z == 0) ? WqT8 : ((z == 1) ? WkT8 : WvT8);
  const int tx = threadIdx.x, ty = threadIdx.y;   // 32 x 8
  const int bx = blockIdx.x, by = blockIdx.y;
  const int ft = ty * 32 + tx;
  if (z == 0 && by == 0 && ft < 128) csum[bx * 128 + ft] = 0.f;  // 4096 f32
#pragma unroll
  for (int i = 0; i < 4; ++i)
    tile[ty + i * 8][tx] = W[(size_t)(by * 32 + ty + i * 8) * CD + bx * 32 + tx];
  __syncthreads();
#pragma unroll
  for (int i = 0; i < 4; ++i)
    WT[(size_t)(bx * 32 + ty + i * 8) * CD + by * 32 + tx] =
        f2fp8(tile[tx][ty + i * 8]);
}

// ---------------------------------------------------------------------------
// EXACT vsum: vsum[b][d] = sum_k csum[b][k]*Wv[k][d] + 2048*bv[d]  (all f32)
// ---------------------------------------------------------------------------
__global__ __launch_bounds__(256) void vsum_mv_kernel(
    const float* __restrict__ csum, const float* __restrict__ Wv,
    const float* __restrict__ bv, float* __restrict__ vsum)
{
  __shared__ float sh[256];
  const int dc = blockIdx.x, b = blockIdx.y;
  const int tid = threadIdx.x;
  const int dl = tid & 127, kh = tid >> 7;
  const int d = dc * 128 + dl;
  const float* cb = csum + b * CD;
  float p0 = 0.f, p1 = 0.f, p2 = 0.f, p3 = 0.f;
  const int k0 = kh * 512;
  for (int k = k0; k < k0 + 512; k += 4) {
    p0 += cb[k + 0] * Wv[(size_t)(k + 0) * CD + d];
    p1 += cb[k + 1] * Wv[(size_t)(k + 1) * CD + d];
    p2 += cb[k + 2] * Wv[(size_t)(k + 2) * CD + d];
    p3 += cb[k + 3] * Wv[(size_t)(k + 3) * CD + d];
  }
  sh[tid] = (p0 + p1) + (p2 + p3);
  __syncthreads();
  if (tid < 128)
    vsum[b * CD + dc * 128 + tid] =
        sh[tid] + sh[tid + 128] + 2048.0f * bv[dc * 128 + tid];
}

// ---------------------------------------------------------------------------
// fused Q|K projections (128^2 fp8 core): grid (64,16)=1024, 2 clean rounds.
// ---------------------------------------------------------------------------
__global__ __launch_bounds__(256, 2) void qk_kernel(
    const u8* __restrict__ x1f8, const u8* __restrict__ x2f8,
    const u8* __restrict__ WqT8, const u8* __restrict__ WkT8,
    const float* __restrict__ bq, const float* __restrict__ bk,
    u8* __restrict__ Qf8, u8* __restrict__ Kf8)
{
  extern __shared__ char smem_raw[];
  const int flat = blockIdx.y * 64 + blockIdx.x;      // nwg=1024
  const int s = (flat & 7) * 128 + (flat >> 3);       // XCD swizzle
  const int bx = s & 63, by = s >> 6;
  const int sel = by >> 3;
  const int m0 = bx * 128, n0 = (by & 7) * 128;
  const u8* A  = sel ? x2f8 : x1f8;
  const u8* Bt = sel ? WkT8 : WqT8;
  const float* bias = sel ? bk : bq;
  u8* Y = sel ? Kf8 : Qf8;

  f32x4 acc[4][4] = {};
  gemm_f8_128(A, CD, Bt, CD, m0, n0, CD, smem_raw, acc);

  const int tid = threadIdx.x, lane = tid & 63, wid = tid >> 6;
  const int wr = wid >> 1, wc = wid & 1, lr = lane & 15, kg = lane >> 4;
#pragma unroll
  for (int mi = 0; mi < 4; ++mi)
#pragma unroll
    for (int ni = 0; ni < 4; ++ni) {
      const int col = n0 + wc * 64 + ni * 16 + lr;
      const float bcol = bias[col];
#pragma unroll
      for (int j = 0; j < 4; ++j) {
        const int row = m0 + wr * 64 + mi * 16 + kg * 4 + j;
        Y[(size_t)row * CD + col] = f2fp8(acc[mi][ni][j] + bcol);
      }
    }
}

// ---------------------------------------------------------------------------
// V projection (128^2 fp8 core) -> Vt8[b][d][n] via LDS transpose.
// grid (64,8)=512, 1 clean round.
// ---------------------------------------------------------------------------
__global__ __launch_bounds__(256, 2) void v_kernel(
    const u8* __restrict__ x2f8, const u8* __restrict__ WvT8,
    const float* __restrict__ bv, u8* __restrict__ Vt8)
{
  extern __shared__ char smem_raw[];
  const int flat = blockIdx.y * 64 + blockIdx.x;      // nwg=512
  const int s = (flat & 7) * 64 + (flat >> 3);
  const int bx = s & 63, by = s >> 6;                 // 64 m-tiles, 8 d-tiles
  const int m0 = bx * 128, n0 = by * 128;

  f32x4 acc[4][4] = {};
  gemm_f8_128(x2f8, CD, WvT8, CD, m0, n0, CD, smem_raw, acc);

  const int tid = threadIdx.x, lane = tid & 63, wid = tid >> 6;
  const int wr = wid >> 1, wc = wid & 1, lr = lane & 15, kg = lane >> 4;
  const int b = m0 >> 11;              // batch
  const int nwb = m0 & (CN - 1);       // n-offset within batch
  u8* ldsT = (u8*)smem_raw;            // [128 d][136] u8 = 17.4KB

#pragma unroll
  for (int ni = 0; ni < 4; ++ni) {
    const int cl = wc * 64 + ni * 16 + lr;           // d within tile, 0..127
    const float bcol = bv[n0 + cl];
#pragma unroll
    for (int mi = 0; mi < 4; ++mi) {
      const int rowb = wr * 64 + mi * 16 + kg * 4;   // n within tile, 4-aligned
      *(u32*)(ldsT + cl * 136 + rowb) =
          pk_fp8x4(acc[mi][ni][0] + bcol, acc[mi][ni][1] + bcol,
                   acc[mi][ni][2] + bcol, acc[mi][ni][3] + bcol);
    }
  }
  WAITL();
  SBAR();
  // coalesced copy-out: 128 d x 128 n fp8 = 1024 16B chunks, 4/thread
#pragma unroll
  for (int i = 0; i < 4; ++i) {
    const int c = tid + i * 256;
    const int dl = c >> 3;             // 0..127
    const int nk = c & 7;              // 16B chunk
    i32x4 vv = *(const i32x4*)(ldsT + dl * 136 + nk * 16);
    *(i32x4*)(Vt8 + ((size_t)b * CD + n0 + dl) * CN + nwb + nk * 16) = vv;
  }
}

// ---------------------------------------------------------------------------
// P/4 = exp(Q*K^T/32)/4 (fp8), row sums l (f32) via atomics.
// grid (16,16,4)=1024, 2 clean rounds.
// ---------------------------------------------------------------------------
__global__ __launch_bounds__(256, 2) void scores_kernel(
    const u8* __restrict__ Q, const u8* __restrict__ Km,
    u8* __restrict__ P, float* __restrict__ lsum)
{
  extern __shared__ char smem_raw[];
  const int flat = (blockIdx.z * 16 + blockIdx.y) * 16 + blockIdx.x;  // 1024
  const int s = (flat & 7) * 128 + (flat >> 3);
  const int bx = s & 15, by = (s >> 4) & 15, bz = s >> 8;
  const int m0 = bx * 128, n0 = by * 128;
  const u8* A  = Q  + (size_t)bz * CN * CD;
  const u8* Bt = Km + (size_t)bz * CN * CD;

  f32x4 acc[4][4] = {};
  gemm_f8_128(A, CD, Bt, CD, m0, n0, CD, smem_raw, acc);

  const int tid = threadIdx.x, lane = tid & 63, wid = tid >> 6;
  const int wr = wid >> 1, wc = wid & 1, lr = lane & 15, kg = lane >> 4;
  u8* Pb = P + (size_t)bz * CN * CN;
  float* lb = lsum + (size_t)bz * CN;
  const float sc = 0.03125f * 1.4426950408889634f;
#pragma unroll
  for (int mi = 0; mi < 4; ++mi) {
    float rs[4] = {0.f, 0.f, 0.f, 0.f};
#pragma unroll
    for (int ni = 0; ni < 4; ++ni) {
      const int col = n0 + wc * 64 + ni * 16 + lr;
#pragma unroll
      for (int j = 0; j < 4; ++j) {
        const int row = m0 + wr * 64 + mi * 16 + kg * 4 + j;
        const float pv = exp2f(acc[mi][ni][j] * sc);
        rs[j] += pv;
        Pb[(size_t)row * CN + col] = f2fp8(pv * 0.25f);
      }
    }
#pragma unroll
    for (int j = 0; j < 4; ++j) {
      float v = rs[j];
      v += __shfl_xor(v, 1);
      v += __shfl_xor(v, 2);
      v += __shfl_xor(v, 4);
      v += __shfl_xor(v, 8);
      if (lr == 0)
        atomicAdd(&lb[m0 + wr * 64 + mi * 16 + kg * 4 + j], v);
    }
  }
}

// ---------------------------------------------------------------------------
// ctx = (vsum - 4*(P/4 @ V)/l) / (N-1)  -> bf16. grid (16,8,4)=512, 1 round.
// ---------------------------------------------------------------------------
__global__ __launch_bounds__(256, 2) void pv_kernel(
    const u8* __restrict__ P, const u8* __restrict__ Vt,
    const float* __restrict__ lsum, const float* __restrict__ vsum,
    u16* __restrict__ ctx)
{
  extern __shared__ char smem_raw[];
  const int flat = (blockIdx.z * 8 + blockIdx.y) * 16 + blockIdx.x;  // 512
  const int s = (flat & 7) * 64 + (flat >> 3);
  const int bx = s & 15, by = (s >> 4) & 7, bz = s >> 7;
  const int m0 = bx * 128, n0 = by * 128;
  const u8* A  = P  + (size_t)bz * CN * CN;   // [2048][2048] fp8
  const u8* Bt = Vt + (size_t)bz * CD * CN;   // [1024][2048] fp8

  f32x4 acc[4][4] = {};
  gemm_f8_128(A, CN, Bt, CN, m0, n0, CN, smem_raw, acc);

  const int tid = threadIdx.x, lane = tid & 63, wid = tid >> 6;
  const int wr = wid >> 1, wc = wid & 1, lr = lane & 15, kg = lane >> 4;
  const float inv_nm1 = 1.0f / (float)(CN - 1);
#pragma unroll
  for (int mi = 0; mi < 4; ++mi)
#pragma unroll
    for (int j = 0; j < 4; ++j) {
      const int row = m0 + wr * 64 + mi * 16 + kg * 4 + j;
      const float rl = 4.0f / lsum[(size_t)bz * CN + row];
#pragma unroll
      for (int ni = 0; ni < 4; ++ni) {
        const int col = n0 + wc * 64 + ni * 16 + lr;
        const float cv = (vsum[bz * CD + col] - acc[mi][ni][j] * rl) * inv_nm1;
        ctx[(size_t)(bz * CN + row) * CD + col] = f2bf(cv);
      }
    }
}

// LayerNorm + ReLU per row of 1024: bf16 ctx in, f32 out
__global__ __launch_bounds__(256) void ln_relu_kernel(
    const u16* __restrict__ ctx, const float* __restrict__ gamma,
    const float* __restrict__ beta, float* __restrict__ out)
{
  const u16* x = ctx + (size_t)blockIdx.x * CD;
  const int t = threadIdx.x;
  const ushort4 uv = ((const ushort4*)x)[t];
  float v0 = bf2f(uv.x), v1 = bf2f(uv.y), v2 = bf2f(uv.z), v3 = bf2f(uv.w);
  float s = v0 + v1 + v2 + v3;
  float q = v0 * v0 + v1 * v1 + v2 * v2 + v3 * v3;
#pragma unroll
  for (int off = 1; off < 64; off <<= 1) {
    s += __shfl_xor(s, off);
    q += __shfl_xor(q, off);
  }
  __shared__ float ss[4], qq[4];
  const int w = t >> 6, lane = t & 63;
  if (lane == 0) { ss[w] = s; qq[w] = q; }
  __syncthreads();
  s = ss[0] + ss[1] + ss[2] + ss[3];
  q = qq[0] + qq[1] + qq[2] + qq[3];
  const float mean = s * (1.0f / CD);
  const float var  = q * (1.0f / CD) - mean * mean;
  const float rstd = rsqrtf(var + 1e-5f);
  const float4 g  = ((const float4*)gamma)[t];
  const float4 bb = ((const float4*)beta)[t];
  float4 o;
  o.x = fmaxf(0.f, (v0 - mean) * rstd * g.x + bb.x);
  o.y = fmaxf(0.f, (v1 - mean) * rstd * g.y + bb.y);
  o.z = fmaxf(0.f, (v2 - mean) * rstd * g.z + bb.z);
  o.w = fmaxf(0.f, (v3 - mean) * rstd * g.w + bb.w);
  ((float4*)(out + (size_t)blockIdx.x * CD))[t] = o;
}

// ---------------------------------------------------------------------------
extern "C" void kernel_launch(void* const* d_in, const int* in_sizes, int n_in,
                              void* d_out, int out_size, void* d_ws, size_t ws_size,
                              hipStream_t stream)
{
  (void)in_sizes; (void)n_in; (void)out_size; (void)ws_size;
  const float* x1    = (const float*)d_in[0];
  const float* x2    = (const float*)d_in[1];
  const float* Wq    = (const float*)d_in[2];
  const float* bq    = (const float*)d_in[3];
  const float* Wk    = (const float*)d_in[4];
  const float* bk    = (const float*)d_in[5];
  const float* Wv    = (const float*)d_in[6];
  const float* bv    = (const float*)d_in[7];
  const float* gamma = (const float*)d_in[8];
  const float* beta  = (const float*)d_in[9];
  float* out = (float*)d_out;

  const int LDS_CORE = 65536;
  hipFuncSetAttribute((const void*)qk_kernel,
                      hipFuncAttributeMaxDynamicSharedMemorySize, LDS_CORE);
  hipFuncSetAttribute((const void*)scores_kernel,
                      hipFuncAttributeMaxDynamicSharedMemorySize, LDS_CORE);
  hipFuncSetAttribute((const void*)v_kernel,
                      hipFuncAttributeMaxDynamicSharedMemorySize, LDS_CORE);
  hipFuncSetAttribute((const void*)pv_kernel,
                      hipFuncAttributeMaxDynamicSharedMemorySize, LDS_CORE);

  char* p = (char*)d_ws;
  auto alloc = [&](size_t bytes) -> char* {
    char* r = p;
    p += (bytes + 255) & ~(size_t)255;
    return r;
  };
  u8*  x1f8  = (u8*)alloc((size_t)CM * CD);
  u8*  x2f8  = (u8*)alloc((size_t)CM * CD);
  u8*  WqT8  = (u8*)alloc((size_t)CD * CD);
  u8*  WkT8  = (u8*)alloc((size_t)CD * CD);
  u8*  WvT8  = (u8*)alloc((size_t)CD * CD);
  u8*  Qf8   = (u8*)alloc((size_t)CM * CD);
  u8*  Kf8   = (u8*)alloc((size_t)CM * CD);
  u8*  Vt8   = (u8*)alloc((size_t)CM * CD);
  u8*  Pf8   = (u8*)alloc((size_t)CB * CN * CN);
  u16* ctxb  = (u16*)alloc((size_t)CM * CD * 2);
  float* ls  = (float*)alloc((size_t)CB * CN * 4);
  float* vs  = (float*)alloc((size_t)CB * CD * 4);
  float* cs  = (float*)alloc((size_t)CB * CD * 4);

  // W transposes -> fp8 + zero csum (must precede cvt)
  {
    dim3 g(32, 32, 3), blk(32, 8);
    transpose_w_kernel<<<g, blk, 0, stream>>>(Wq, Wk, Wv, WqT8, WkT8, WvT8, cs);
  }

  // f32 -> fp8 inputs + exact colsum(x2) partials + zero lsum
  {
    dim3 g(256, 2);
    cvt_kernel<<<g, 256, 0, stream>>>(x1, x1f8, x2, x2f8, cs, ls);
  }

  // exact vsum = colsum(x2).Wv + 2048*bv  (f32)
  {
    dim3 g(8, CB);
    vsum_mv_kernel<<<g, 256, 0, stream>>>(cs, Wv, bv, vs);
  }

  // fused Q|K projections (fp8 128^2 core, 1024 blocks)
  {
    dim3 g(64, 16);
    qk_kernel<<<g, 256, LDS_CORE, stream>>>(x1f8, x2f8, WqT8, WkT8, bq, bk,
                                            Qf8, Kf8);
  }

  // V projection -> Vt8 (512 blocks)
  {
    dim3 g(64, 8);
    v_kernel<<<g, 256, LDS_CORE, stream>>>(x2f8, WvT8, bv, Vt8);
  }

  // P/4 = exp(QK^T/32)/4 (fp8), l = rowsum (1024 blocks)
  {
    dim3 g(16, 16, CB);
    scores_kernel<<<g, 256, LDS_CORE, stream>>>(Qf8, Kf8, Pf8, ls);
  }

  // ctx = (vsum - 4*P@V/l)/(N-1) -> bf16 (512 blocks)
  {
    dim3 g(16, 8, CB);
    pv_kernel<<<g, 256, LDS_CORE, stream>>>(Pf8, Vt8, ls, vs, ctxb);
  }

  // LayerNorm + ReLU (bf16 in, f32 out)
  ln_relu_kernel<<<CM, 256, 0, stream>>>(ctxb, gamma, beta, out);
}